// Round 12
// baseline (822.021 us; speedup 1.0000x reference)
//
#include <hip/hip_runtime.h>
#include <hip/hip_bf16.h>
#include <stdint.h>

#define T_NUM 1024
#define H_DIM 2048
#define E_NUM 16
#define TOPK 4
#define I_DIM 1408
#define SHI_DIM 2816

typedef __attribute__((ext_vector_type(4))) float f32x4;
typedef __attribute__((ext_vector_type(8))) short bf16x8;

static __device__ __forceinline__ short f2bf(float f) {
    __hip_bfloat16 h = __float2bfloat16(f);
    return __builtin_bit_cast(short, h);
}
static __device__ __forceinline__ float bf2f(short s) {
    return __bfloat162float(__builtin_bit_cast(__hip_bfloat16, s));
}

// ---------------- router: fp32 logits -> softmax -> top4 (+ x -> bf16) ------
__global__ void router_kernel(const float* __restrict__ x, const float* __restrict__ wgate,
                              int* __restrict__ top_e, float* __restrict__ top_w,
                              short* __restrict__ xb) {
    const int t = blockIdx.x;
    const int tid = threadIdx.x;       // 256 threads
    __shared__ float xsh[H_DIM];
    const float* xr = x + (size_t)t * H_DIM;
    for (int h = tid; h < H_DIM; h += 256) xsh[h] = xr[h];
    __syncthreads();

    {   // bf16 copy of x
        short v[8];
        #pragma unroll
        for (int i = 0; i < 8; ++i) v[i] = f2bf(xsh[tid * 8 + i]);
        *reinterpret_cast<bf16x8*>(xb + (size_t)t * H_DIM + tid * 8) = *(bf16x8*)v;
    }

    const int e = tid >> 4;            // 0..15
    const int j = tid & 15;
    const float* wr = wgate + (size_t)e * H_DIM;
    float acc = 0.f;
    for (int h = j; h < H_DIM; h += 16) acc += xsh[h] * wr[h];
    #pragma unroll
    for (int m = 8; m >= 1; m >>= 1) acc += __shfl_down(acc, m, 16);

    __shared__ float logits[E_NUM];
    if (j == 0) logits[e] = acc;
    __syncthreads();

    if (tid == 0) {
        float mx = logits[0];
        #pragma unroll
        for (int i = 1; i < E_NUM; ++i) mx = fmaxf(mx, logits[i]);
        float p[E_NUM]; float s = 0.f;
        #pragma unroll
        for (int i = 0; i < E_NUM; ++i) { p[i] = expf(logits[i] - mx); s += p[i]; }
        const float inv = 1.f / s;
        #pragma unroll
        for (int i = 0; i < E_NUM; ++i) p[i] *= inv;
        for (int k = 0; k < TOPK; ++k) {
            float best = -1.f; int bi = 0;
            #pragma unroll
            for (int i = 0; i < E_NUM; ++i) if (p[i] > best) { best = p[i]; bi = i; }
            top_e[t * TOPK + k] = bi;
            top_w[t * TOPK + k] = best;
            p[bi] = -2.f;
        }
    }
}

// ------- stable bucket sort of 4096 slots by expert (deterministic) -------
__global__ void perm_kernel(const int* __restrict__ top_e,
                            int* __restrict__ offs, int* __restrict__ perm) {
    __shared__ int cnt[256][E_NUM];
    __shared__ int base[E_NUM];
    const int tid = threadIdx.x;
    int c[E_NUM];
    #pragma unroll
    for (int i = 0; i < E_NUM; ++i) c[i] = 0;
    for (int s = tid * 16; s < tid * 16 + 16; ++s) c[top_e[s]]++;
    #pragma unroll
    for (int i = 0; i < E_NUM; ++i) cnt[tid][i] = c[i];
    __syncthreads();
    if (tid < E_NUM) {
        int run = 0;
        for (int b = 0; b < 256; ++b) { int v = cnt[b][tid]; cnt[b][tid] = run; run += v; }
        base[tid] = run;
    }
    __syncthreads();
    if (tid == 0) {
        int run = 0;
        for (int e2 = 0; e2 < E_NUM; ++e2) { int v = base[e2]; base[e2] = run; offs[e2] = run; run += v; }
        offs[E_NUM] = run;
    }
    __syncthreads();
    int run[E_NUM];
    #pragma unroll
    for (int i = 0; i < E_NUM; ++i) run[i] = base[i] + cnt[tid][i];
    for (int s = tid * 16; s < tid * 16 + 16; ++s) {
        int e2 = top_e[s];
        perm[run[e2]++] = s;
    }
}

// ------- SwiGLU combine: act = silu(g) * u  (bf16 elementwise) -------
__global__ void swiglu_kernel(const short* __restrict__ g, const short* __restrict__ u,
                              short* __restrict__ act, int n8) {
    const int i = blockIdx.x * 256 + threadIdx.x;
    if (i >= n8) return;
    bf16x8 gv = *reinterpret_cast<const bf16x8*>(g + (size_t)i * 8);
    bf16x8 uv = *reinterpret_cast<const bf16x8*>(u + (size_t)i * 8);
    short o[8];
    #pragma unroll
    for (int j = 0; j < 8; ++j) {
        float gf = bf2f(gv[j]);
        float uf = bf2f(uv[j]);
        o[j] = f2bf(gf / (1.f + __expf(-gf)) * uf);
    }
    *reinterpret_cast<bf16x8*>(act + (size_t)i * 8) = *(bf16x8*)o;
}

// ------- final combine: out[t][h] += sum_k dr[4t+k][h]  (dr pre-weighted) -------
__global__ void combine_kernel(const short* __restrict__ dr, float* __restrict__ out) {
    const int i = blockIdx.x * 256 + threadIdx.x;   // one per 8 cols of a token
    const int t = i >> 8;                            // H_DIM/8 = 256
    const int h8 = (i & 255) * 8;
    float s[8];
    f32x4 o0 = *reinterpret_cast<const f32x4*>(out + (size_t)t * H_DIM + h8);
    f32x4 o1 = *reinterpret_cast<const f32x4*>(out + (size_t)t * H_DIM + h8 + 4);
    #pragma unroll
    for (int j = 0; j < 4; ++j) { s[j] = o0[j]; s[4 + j] = o1[j]; }
    #pragma unroll
    for (int k = 0; k < TOPK; ++k) {
        bf16x8 v = *reinterpret_cast<const bf16x8*>(dr + ((size_t)(t * TOPK + k)) * H_DIM + h8);
        #pragma unroll
        for (int j = 0; j < 8; ++j) s[j] += bf2f(v[j]);
    }
    f32x4 r0 = { s[0], s[1], s[2], s[3] };
    f32x4 r1 = { s[4], s[5], s[6], s[7] };
    *reinterpret_cast<f32x4*>(out + (size_t)t * H_DIM + h8) = r0;
    *reinterpret_cast<f32x4*>(out + (size_t)t * H_DIM + h8 + 4) = r1;
}

// ---- depth-2 register-pipelined GEMM: 128 thr = 2 independent waves, no LDS,
//      no barriers. Each wave: 32M x 64N tile; per K-step 34 VMEM (2 b128 A +
//      32 dword B) issued one full step ahead -> auto-waitcnt = vmcnt(34).
// A bf16 [rows][K] k-contig; B f32 [K][N] native (cvt in register).
// MODE 0: routed gate|up : A=xb gathered; ntt<nsplit ? B1->Out1 : B2->Out2 (bf16)
// MODE 1: shared gate|up : dense A
// MODE 2: routed down    : A=act_r gathered; B=wd[e]; dr[slot] = w*v (bf16)
// MODE 3: shared down    : A=act_s dense;    B=sd;    f32 store
template<int MODE>
__global__ __launch_bounds__(128) void gemm_p2(
    const short* __restrict__ A,
    const float* __restrict__ B1g, const float* __restrict__ B2g,
    void* __restrict__ Out1v, void* __restrict__ Out2v,
    const int* __restrict__ perm, const int* __restrict__ offs,
    const float* __restrict__ top_w, int nmt, int nnt, int nsplit)
{
    constexpr int KD  = (MODE <= 1) ? H_DIM : (MODE == 2 ? I_DIM : SHI_DIM);
    constexpr int LDB = (MODE == 0) ? I_DIM : (MODE == 1) ? SHI_DIM : H_DIM;
    constexpr int NK  = KD / 32;    // 64 / 64 / 44 / 88 -- all even, >= 4

    const int tid  = threadIdx.x;
    const int lane = tid & 63;
    const int wid  = tid >> 6;      // 0..1, independent waves

    // bijective XCD swizzle, mt innermost (same-strip readers co-resident on one XCD)
    int wgid = blockIdx.x;
    {
        const int nwg = gridDim.x;
        const int qq = nwg >> 3, rr = nwg & 7;
        const int xcd = wgid & 7, lin = wgid >> 3;
        wgid = (xcd < rr ? xcd * (qq + 1) : rr * (qq + 1) + (xcd - rr) * qq) + lin;
    }
    const int mt  = wgid % nmt;
    const int ntt = (wgid / nmt) % nnt;
    const int e   = wgid / (nmt * nnt);

    int off = 0, cnt = T_NUM;
    const float* B1 = B1g;
    const float* B2 = B2g;
    if constexpr (MODE == 0) {
        off = offs[e]; cnt = offs[e + 1] - off;
        if (mt * 64 >= cnt) return;
        B1 = B1g + (size_t)e * H_DIM * I_DIM;
        B2 = B2g + (size_t)e * H_DIM * I_DIM;
    }
    if constexpr (MODE == 2) {
        off = offs[e]; cnt = offs[e + 1] - off;
        if (mt * 64 >= cnt) return;
        B1 = B1g + (size_t)e * I_DIM * H_DIM;
    }
    const float* Bsel = (ntt < nsplit) ? B1 : B2;
    const int ncol = (ntt % nsplit) * 64;
    const int rb = mt * 64 + wid * 32;      // this wave's row base

    // A row pointers (row = rb + mi*16 + (lane&15))
    const short* Ap0;
    const short* Ap1;
    {
        int gm0 = rb + (lane & 15);
        int gm1 = gm0 + 16;
        int ra0, ra1;
        if constexpr (MODE == 0) {
            ra0 = perm[off + (gm0 < cnt ? gm0 : cnt - 1)] >> 2;
            ra1 = perm[off + (gm1 < cnt ? gm1 : cnt - 1)] >> 2;
        } else if constexpr (MODE == 2) {
            ra0 = perm[off + (gm0 < cnt ? gm0 : cnt - 1)];
            ra1 = perm[off + (gm1 < cnt ? gm1 : cnt - 1)];
        } else {
            ra0 = gm0; ra1 = gm1;
        }
        Ap0 = A + (size_t)ra0 * KD;
        Ap1 = A + (size_t)ra1 * KD;
    }

    const int koff = (lane >> 4) * 8;                    // 0,8,16,24
    const float* Bp = Bsel + (size_t)koff * LDB + ncol + (lane & 15);

    f32x4 acc[2][4];
    #pragma unroll
    for (int i = 0; i < 2; ++i)
        #pragma unroll
        for (int j = 0; j < 4; ++j) acc[i][j] = (f32x4)0.f;

    // two named staging sets (depth-2); literal indices only (fully unrolled)
    bf16x8 aS0_0, aS0_1, aS1_0, aS1_1;
    float bS0[32], bS1[32];

    auto load0 = [&](int kt) {
        const int k0 = kt * 32;
        aS0_0 = *reinterpret_cast<const bf16x8*>(Ap0 + k0 + koff);
        aS0_1 = *reinterpret_cast<const bf16x8*>(Ap1 + k0 + koff);
        const float* bp = Bp + (size_t)k0 * LDB;
        #pragma unroll
        for (int j = 0; j < 8; ++j) {
            const float* r = bp + (size_t)j * LDB;
            #pragma unroll
            for (int c = 0; c < 4; ++c) bS0[j * 4 + c] = r[c * 16];
        }
    };
    auto load1 = [&](int kt) {
        const int k0 = kt * 32;
        aS1_0 = *reinterpret_cast<const bf16x8*>(Ap0 + k0 + koff);
        aS1_1 = *reinterpret_cast<const bf16x8*>(Ap1 + k0 + koff);
        const float* bp = Bp + (size_t)k0 * LDB;
        #pragma unroll
        for (int j = 0; j < 8; ++j) {
            const float* r = bp + (size_t)j * LDB;
            #pragma unroll
            for (int c = 0; c < 4; ++c) bS1[j * 4 + c] = r[c * 16];
        }
    };
    auto comp0 = [&]() {
        bf16x8 bf[4];
        #pragma unroll
        for (int c = 0; c < 4; ++c) {
            #pragma unroll
            for (int j = 0; j < 8; ++j) bf[c][j] = f2bf(bS0[j * 4 + c]);
        }
        #pragma unroll
        for (int c = 0; c < 4; ++c) {
            acc[0][c] = __builtin_amdgcn_mfma_f32_16x16x32_bf16(aS0_0, bf[c], acc[0][c], 0, 0, 0);
            acc[1][c] = __builtin_amdgcn_mfma_f32_16x16x32_bf16(aS0_1, bf[c], acc[1][c], 0, 0, 0);
        }
    };
    auto comp1 = [&]() {
        bf16x8 bf[4];
        #pragma unroll
        for (int c = 0; c < 4; ++c) {
            #pragma unroll
            for (int j = 0; j < 8; ++j) bf[c][j] = f2bf(bS1[j * 4 + c]);
        }
        #pragma unroll
        for (int c = 0; c < 4; ++c) {
            acc[0][c] = __builtin_amdgcn_mfma_f32_16x16x32_bf16(aS1_0, bf[c], acc[0][c], 0, 0, 0);
            acc[1][c] = __builtin_amdgcn_mfma_f32_16x16x32_bf16(aS1_1, bf[c], acc[1][c], 0, 0, 0);
        }
    };

    // depth-2 software pipeline: step t computes while step t+1's loads fly
    load0(0);
    for (int kt = 0; kt < NK - 2; kt += 2) {
        load1(kt + 1);
        __builtin_amdgcn_sched_barrier(0);
        comp0();                               // auto-waitcnt vmcnt(34)
        load0(kt + 2);
        __builtin_amdgcn_sched_barrier(0);
        comp1();
    }
    load1(NK - 1);
    __builtin_amdgcn_sched_barrier(0);
    comp0();
    comp1();

    // epilogue: C layout row=(lane>>4)*4+j, col=lane&15 within each 16x16 tile
    #pragma unroll
    for (int mi = 0; mi < 2; ++mi) {
        #pragma unroll
        for (int j = 0; j < 4; ++j) {
            const int r = rb + mi * 16 + (lane >> 4) * 4 + j;
            if constexpr (MODE == 0 || MODE == 2) { if (r >= cnt) continue; }
            #pragma unroll
            for (int nt2 = 0; nt2 < 4; ++nt2) {
                const int n = ncol + nt2 * 16 + (lane & 15);
                const float v = acc[mi][nt2][j];
                if constexpr (MODE == 0) {
                    int orow = perm[off + r];
                    short* o = (short*)((ntt < nsplit) ? Out1v : Out2v);
                    o[(size_t)orow * I_DIM + n] = f2bf(v);
                } else if constexpr (MODE == 1) {
                    short* o = (short*)((ntt < nsplit) ? Out1v : Out2v);
                    o[(size_t)r * SHI_DIM + n] = f2bf(v);
                } else if constexpr (MODE == 2) {
                    int s = perm[off + r];
                    ((short*)Out1v)[(size_t)s * H_DIM + n] = f2bf(v * top_w[s]);
                } else {
                    ((float*)Out1v)[(size_t)r * H_DIM + n] = v;
                }
            }
        }
    }
}

extern "C" void kernel_launch(void* const* d_in, const int* in_sizes, int n_in,
                              void* d_out, int out_size, void* d_ws, size_t ws_size,
                              hipStream_t stream) {
    const float* x     = (const float*)d_in[0];
    const float* wgate = (const float*)d_in[1];
    const float* wg    = (const float*)d_in[2];
    const float* wu    = (const float*)d_in[3];
    const float* wd    = (const float*)d_in[4];
    const float* sg    = (const float*)d_in[5];
    const float* su    = (const float*)d_in[6];
    const float* sd    = (const float*)d_in[7];
    float* out = (float*)d_out;

    uintptr_t p = (uintptr_t)d_ws;
    auto alloc = [&](size_t bytes) {
        p = (p + 255) & ~(uintptr_t)255;
        void* r = (void*)p; p += bytes; return r;
    };
    int*   top_e = (int*)alloc((size_t)T_NUM * TOPK * sizeof(int));
    float* top_w = (float*)alloc((size_t)T_NUM * TOPK * sizeof(float));
    int*   offs  = (int*)alloc((E_NUM + 1) * sizeof(int));
    int*   perm  = (int*)alloc((size_t)T_NUM * TOPK * sizeof(int));
    short* xb    = (short*)alloc((size_t)T_NUM * H_DIM * 2);
    short* g_r   = (short*)alloc((size_t)T_NUM * TOPK * I_DIM * 2);
    short* u_r   = (short*)alloc((size_t)T_NUM * TOPK * I_DIM * 2);
    short* act_r = (short*)alloc((size_t)T_NUM * TOPK * I_DIM * 2);
    short* g_s   = (short*)alloc((size_t)T_NUM * SHI_DIM * 2);
    short* u_s   = (short*)alloc((size_t)T_NUM * SHI_DIM * 2);
    short* act_s = (short*)alloc((size_t)T_NUM * SHI_DIM * 2);
    short* dr    = (short*)alloc((size_t)T_NUM * TOPK * H_DIM * 2);   // 16.8 MB

    router_kernel<<<T_NUM, 256, 0, stream>>>(x, wgate, top_e, top_w, xb);
    perm_kernel<<<1, 256, 0, stream>>>(top_e, offs, perm);

    const int nnI = I_DIM / 64;     // 22
    const int nnH = H_DIM / 64;     // 32
    const int nnS = SHI_DIM / 64;   // 44

    // shared gate|up (split in one dispatch): nmt=16, grid 16 * 88 = 1408
    gemm_p2<1><<<16 * (2 * nnS), 128, 0, stream>>>(
        xb, sg, su, g_s, u_s, nullptr, nullptr, nullptr, 16, 2 * nnS, nnS);
    swiglu_kernel<<<(T_NUM * SHI_DIM / 8 + 255) / 256, 256, 0, stream>>>(
        g_s, u_s, act_s, T_NUM * SHI_DIM / 8);
    // shared down: grid 16 * 32 = 512 (plain stores init out)
    gemm_p2<3><<<16 * nnH, 128, 0, stream>>>(
        act_s, sd, nullptr, out, nullptr, nullptr, nullptr, nullptr, 16, nnH, nnH);

    // routed gate|up per expert: grid 16 * 44 * 16 = 11264
    gemm_p2<0><<<16 * (2 * nnI) * E_NUM, 128, 0, stream>>>(
        xb, wg, wu, g_r, u_r, perm, offs, nullptr, 16, 2 * nnI, nnI);
    swiglu_kernel<<<(T_NUM * TOPK * I_DIM / 8 + 255) / 256, 256, 0, stream>>>(
        g_r, u_r, act_r, T_NUM * TOPK * I_DIM / 8);
    // routed down per expert: grid 16 * 32 * 16 = 8192
    gemm_p2<2><<<16 * nnH * E_NUM, 128, 0, stream>>>(
        act_r, wd, nullptr, dr, nullptr, perm, offs, top_w, 16, nnH, nnH);
    // out[t] += sum_k dr[4t+k]
    combine_kernel<<<T_NUM * H_DIM / 8 / 256, 256, 0, stream>>>(dr, out);
}

// Round 13
// 629.107 us; speedup vs baseline: 1.3066x; 1.3066x over previous
//
#include <hip/hip_runtime.h>
#include <hip/hip_bf16.h>
#include <stdint.h>

#define T_NUM 1024
#define H_DIM 2048
#define E_NUM 16
#define TOPK 4
#define I_DIM 1408
#define SHI_DIM 2816

typedef __attribute__((ext_vector_type(4))) float f32x4;
typedef __attribute__((ext_vector_type(8))) short bf16x8;
typedef __attribute__((ext_vector_type(4))) short s16x4;

static __device__ __forceinline__ short f2bf(float f) {
    __hip_bfloat16 h = __float2bfloat16(f);
    return __builtin_bit_cast(short, h);
}
static __device__ __forceinline__ float bf2f(short s) {
    return __bfloat162float(__builtin_bit_cast(__hip_bfloat16, s));
}

static __device__ __forceinline__ void gll16(const short* g, const short* l) {
    __builtin_amdgcn_global_load_lds(
        (const __attribute__((address_space(1))) void*)g,
        (__attribute__((address_space(3))) void*)l, 16, 0, 0);
}

// ---------------- router: fp32 logits -> softmax -> top4 (+ x -> bf16) ------
__global__ void router_kernel(const float* __restrict__ x, const float* __restrict__ wgate,
                              int* __restrict__ top_e, float* __restrict__ top_w,
                              short* __restrict__ xb) {
    const int t = blockIdx.x;
    const int tid = threadIdx.x;       // 256 threads
    __shared__ float xsh[H_DIM];
    const float* xr = x + (size_t)t * H_DIM;
    for (int h = tid; h < H_DIM; h += 256) xsh[h] = xr[h];
    __syncthreads();

    {   // bf16 copy of x
        short v[8];
        #pragma unroll
        for (int i = 0; i < 8; ++i) v[i] = f2bf(xsh[tid * 8 + i]);
        *reinterpret_cast<bf16x8*>(xb + (size_t)t * H_DIM + tid * 8) = *(bf16x8*)v;
    }

    const int e = tid >> 4;            // 0..15
    const int j = tid & 15;
    const float* wr = wgate + (size_t)e * H_DIM;
    float acc = 0.f;
    for (int h = j; h < H_DIM; h += 16) acc += xsh[h] * wr[h];
    #pragma unroll
    for (int m = 8; m >= 1; m >>= 1) acc += __shfl_down(acc, m, 16);

    __shared__ float logits[E_NUM];
    if (j == 0) logits[e] = acc;
    __syncthreads();

    if (tid == 0) {
        float mx = logits[0];
        #pragma unroll
        for (int i = 1; i < E_NUM; ++i) mx = fmaxf(mx, logits[i]);
        float p[E_NUM]; float s = 0.f;
        #pragma unroll
        for (int i = 0; i < E_NUM; ++i) { p[i] = expf(logits[i] - mx); s += p[i]; }
        const float inv = 1.f / s;
        #pragma unroll
        for (int i = 0; i < E_NUM; ++i) p[i] *= inv;
        for (int k = 0; k < TOPK; ++k) {
            float best = -1.f; int bi = 0;
            #pragma unroll
            for (int i = 0; i < E_NUM; ++i) if (p[i] > best) { best = p[i]; bi = i; }
            top_e[t * TOPK + k] = bi;
            top_w[t * TOPK + k] = best;
            p[bi] = -2.f;
        }
    }
}

// ------- stable bucket sort of 4096 slots by expert (deterministic) -------
__global__ void perm_kernel(const int* __restrict__ top_e,
                            int* __restrict__ offs, int* __restrict__ perm) {
    __shared__ int cnt[256][E_NUM];
    __shared__ int base[E_NUM];
    const int tid = threadIdx.x;
    int c[E_NUM];
    #pragma unroll
    for (int i = 0; i < E_NUM; ++i) c[i] = 0;
    for (int s = tid * 16; s < tid * 16 + 16; ++s) c[top_e[s]]++;
    #pragma unroll
    for (int i = 0; i < E_NUM; ++i) cnt[tid][i] = c[i];
    __syncthreads();
    if (tid < E_NUM) {
        int run = 0;
        for (int b = 0; b < 256; ++b) { int v = cnt[b][tid]; cnt[b][tid] = run; run += v; }
        base[tid] = run;
    }
    __syncthreads();
    if (tid == 0) {
        int run = 0;
        for (int e2 = 0; e2 < E_NUM; ++e2) { int v = base[e2]; base[e2] = run; offs[e2] = run; run += v; }
        offs[E_NUM] = run;
    }
    __syncthreads();
    int run[E_NUM];
    #pragma unroll
    for (int i = 0; i < E_NUM; ++i) run[i] = base[i] + cnt[tid][i];
    for (int s = tid * 16; s < tid * 16 + 16; ++s) {
        int e2 = top_e[s];
        perm[run[e2]++] = s;
    }
}

// ------- transpose+convert: src f32 [mat][R][C] -> dst bf16 [mat][C][R] -------
__global__ void tconv_kernel(const float* __restrict__ src, short* __restrict__ dst,
                             int R, int C) {
    __shared__ float t[64][65];
    const int c0 = blockIdx.x * 64, r0 = blockIdx.y * 64;
    const size_t mo = (size_t)blockIdx.z * R * C;
    const float* s = src + mo;
    short* d = dst + mo;
    const int tid = threadIdx.x;
    #pragma unroll
    for (int it = 0; it < 4; ++it) {
        const int q = it * 256 + tid;
        const int r = q >> 4, c4 = (q & 15) * 4;
        f32x4 v = *reinterpret_cast<const f32x4*>(s + (size_t)(r0 + r) * C + c0 + c4);
        t[r][c4] = v[0]; t[r][c4 + 1] = v[1]; t[r][c4 + 2] = v[2]; t[r][c4 + 3] = v[3];
    }
    __syncthreads();
    #pragma unroll
    for (int it = 0; it < 2; ++it) {
        const int q = it * 256 + tid;
        const int c = q >> 3, r8 = (q & 7) * 8;
        short v[8];
        #pragma unroll
        for (int i = 0; i < 8; ++i) v[i] = f2bf(t[r8 + i][c]);
        *reinterpret_cast<bf16x8*>(d + (size_t)(c0 + c) * R + r0 + r8) = *(bf16x8*)v;
    }
}

// ------- SwiGLU combine: act = silu(g) * u  (bf16 elementwise) -------
__global__ void swiglu_kernel(const short* __restrict__ g, const short* __restrict__ u,
                              short* __restrict__ act, int n8) {
    const int i = blockIdx.x * 256 + threadIdx.x;
    if (i >= n8) return;
    bf16x8 gv = *reinterpret_cast<const bf16x8*>(g + (size_t)i * 8);
    bf16x8 uv = *reinterpret_cast<const bf16x8*>(u + (size_t)i * 8);
    short o[8];
    #pragma unroll
    for (int j = 0; j < 8; ++j) {
        float gf = bf2f(gv[j]);
        float uf = bf2f(uv[j]);
        o[j] = f2bf(gf / (1.f + __expf(-gf)) * uf);
    }
    *reinterpret_cast<bf16x8*>(act + (size_t)i * 8) = *(bf16x8*)o;
}

// ------- final combine: out[t][h] += sum_k dr[4t+k][h]  (dr pre-weighted) -------
__global__ void combine_kernel(const short* __restrict__ dr, float* __restrict__ out) {
    const int i = blockIdx.x * 256 + threadIdx.x;   // one per 8 cols of a token
    const int t = i >> 8;                            // H_DIM/8 = 256
    const int h8 = (i & 255) * 8;
    float s[8];
    f32x4 o0 = *reinterpret_cast<const f32x4*>(out + (size_t)t * H_DIM + h8);
    f32x4 o1 = *reinterpret_cast<const f32x4*>(out + (size_t)t * H_DIM + h8 + 4);
    #pragma unroll
    for (int j = 0; j < 4; ++j) { s[j] = o0[j]; s[4 + j] = o1[j]; }
    #pragma unroll
    for (int k = 0; k < TOPK; ++k) {
        bf16x8 v = *reinterpret_cast<const bf16x8*>(dr + ((size_t)(t * TOPK + k)) * H_DIM + h8);
        #pragma unroll
        for (int j = 0; j < 8; ++j) s[j] += bf2f(v[j]);
    }
    f32x4 r0 = { s[0], s[1], s[2], s[3] };
    f32x4 r1 = { s[4], s[5], s[6], s[7] };
    *reinterpret_cast<f32x4*>(out + (size_t)t * H_DIM + h8) = r0;
    *reinterpret_cast<f32x4*>(out + (size_t)t * H_DIM + h8 + 4) = r1;
}

// ---------------- bf16 GEMM (R3-verified machine, 3 blocks/CU) ----------------
// A: bf16 [rows][K] k-contig.  B: bf16 [mat][N][K] k-contig (pre-transposed).
// global_load_lds both operands; both-sides XOR swizzle; 2-phase counted vmcnt(4).
// MODE 0: routed up/gate  (A=xb gathered by token; out bf16 [slot][N])
// MODE 1: shared up/gate  (A=xb dense;             out bf16 [row][N])
// MODE 2: routed down     (A=act_r gathered;       out bf16 dr[slot] = w*v)
// MODE 3: shared down     (A=act_s dense;          out f32 store [row][N])
template<int MODE>
__global__ __launch_bounds__(256, 3) void gemm_bf(
    const short* __restrict__ A, int lda, int Kdim,
    const short* __restrict__ Bg,
    void* __restrict__ Outv, int ldo,
    const int* __restrict__ perm, const int* __restrict__ offs,
    const float* __restrict__ top_w, int nmt, int nnt)
{
    constexpr int BK = 32;
    __shared__ __align__(16) short As[2][128 * 32];
    __shared__ __align__(16) short Bs[2][128 * 32];
    __shared__ int   rows_a[128];
    __shared__ int   rows_o[128];
    __shared__ float w_m[128];

    const int tid = threadIdx.x;

    // bijective XCD swizzle, mt innermost (blocks sharing a B-strip share L2)
    int wg = blockIdx.x;
    {
        const int nwg = gridDim.x;
        const int qq = nwg >> 3, rr = nwg & 7;
        const int xcd = wg & 7, lin = wg >> 3;
        wg = (xcd < rr ? xcd * (qq + 1) : rr * (qq + 1) + (xcd - rr) * qq) + lin;
    }
    const int mt = wg % nmt;
    const int nt = (wg / nmt) % nnt;
    const int e  = wg / (nmt * nnt);

    int off = 0, cnt = T_NUM;
    const short* Bt = Bg;
    if constexpr (MODE == 0 || MODE == 2) {
        off = offs[e]; cnt = offs[e + 1] - off;
        if (mt * 128 >= cnt) return;
        Bt = Bg + (size_t)e * ((size_t)nnt * 128) * Kdim;
    }

    if (tid < 128) {
        const int gm = mt * 128 + tid;
        if constexpr (MODE == 0) {
            int s = perm[off + (gm < cnt ? gm : cnt - 1)];
            rows_a[tid] = s >> 2; rows_o[tid] = s; w_m[tid] = 1.f;
        } else if constexpr (MODE == 2) {
            int s = perm[off + (gm < cnt ? gm : cnt - 1)];
            rows_a[tid] = s; rows_o[tid] = s; w_m[tid] = top_w[s];   // dr row = slot
        } else {
            rows_a[tid] = gm; rows_o[tid] = gm; w_m[tid] = 1.f;
        }
    }
    __syncthreads();

    // cache gathered A-row indices in registers (2 chunk-rows per thread)
    int raReg[2];
    #pragma unroll
    for (int it = 0; it < 2; ++it) raReg[it] = rows_a[it * 64 + (tid >> 2)];

    auto stage = [&](int buf, int kt) {
        const int k0 = kt * BK;
        #pragma unroll
        for (int it = 0; it < 2; ++it) {
            const int q = it * 256 + tid;
            const int m = q >> 2;
            const int c = ((q & 3) ^ ((m >> 1) & 3)) * 8;   // pre-swizzled source chunk
            gll16(A + (size_t)raReg[it] * lda + k0 + c, &As[buf][q * 8]);
        }
        #pragma unroll
        for (int it = 0; it < 2; ++it) {
            const int q = it * 256 + tid;
            const int n = q >> 2;
            const int c = ((q & 3) ^ ((n >> 1) & 3)) * 8;
            gll16(Bt + (size_t)(nt * 128 + n) * Kdim + k0 + c, &Bs[buf][q * 8]);
        }
    };

    f32x4 acc[4][4];
    #pragma unroll
    for (int i = 0; i < 4; ++i)
        #pragma unroll
        for (int j = 0; j < 4; ++j) acc[i][j] = (f32x4)0.f;

    const int lane = tid & 63;
    const int wr = (tid >> 7), wc = (tid >> 6) & 1;
    const int lrow = lane & 15;
    const int cswz = (((lane >> 4) ^ ((lrow >> 1) & 3)) * 8);  // same XOR on read side

    auto compute = [&](int buf) {
        bf16x8 af[4];
        #pragma unroll
        for (int mi = 0; mi < 4; ++mi)
            af[mi] = *reinterpret_cast<const bf16x8*>(&As[buf][(wr * 64 + mi * 16 + lrow) * 32 + cswz]);
        #pragma unroll
        for (int ni = 0; ni < 4; ++ni) {
            bf16x8 bfr = *reinterpret_cast<const bf16x8*>(&Bs[buf][(wc * 64 + ni * 16 + lrow) * 32 + cswz]);
            #pragma unroll
            for (int mi = 0; mi < 4; ++mi)
                acc[mi][ni] = __builtin_amdgcn_mfma_f32_16x16x32_bf16(af[mi], bfr, acc[mi][ni], 0, 0, 0);
        }
    };

    const int NK = Kdim / BK;
    stage(0, 0);
    int buf = 0;
    for (int kt = 0; kt < NK; ++kt) {
        if (kt + 1 < NK) {
            stage(buf ^ 1, kt + 1);
            asm volatile("s_waitcnt vmcnt(4)" ::: "memory");  // current buf's 4 loads done
        } else {
            asm volatile("s_waitcnt vmcnt(0)" ::: "memory");
        }
        __builtin_amdgcn_s_barrier();
        compute(buf);
        __builtin_amdgcn_s_barrier();   // all waves done reading buf before it's restaged
        buf ^= 1;
    }

    // epilogue
    #pragma unroll
    for (int mi = 0; mi < 4; ++mi) {
        #pragma unroll
        for (int j = 0; j < 4; ++j) {
            const int ml = wr * 64 + mi * 16 + (lane >> 4) * 4 + j;
            const int gm = mt * 128 + ml;
            if constexpr (MODE == 0 || MODE == 2) { if (gm >= cnt) continue; }
            const int orow = (MODE == 0 || MODE == 2) ? rows_o[ml] : gm;
            const float wsc = w_m[ml];
            #pragma unroll
            for (int ni = 0; ni < 4; ++ni) {
                const int n = nt * 128 + wc * 64 + ni * 16 + (lane & 15);
                const float v = acc[mi][ni][j];
                if constexpr (MODE == 0 || MODE == 1) {
                    ((short*)Outv)[(size_t)orow * ldo + n] = f2bf(v);
                } else if constexpr (MODE == 2) {
                    ((short*)Outv)[(size_t)orow * ldo + n] = f2bf(v * wsc);
                } else {
                    ((float*)Outv)[(size_t)orow * ldo + n] = v;
                }
            }
        }
    }
}

extern "C" void kernel_launch(void* const* d_in, const int* in_sizes, int n_in,
                              void* d_out, int out_size, void* d_ws, size_t ws_size,
                              hipStream_t stream) {
    const float* x     = (const float*)d_in[0];
    const float* wgate = (const float*)d_in[1];
    const float* wg    = (const float*)d_in[2];
    const float* wu    = (const float*)d_in[3];
    const float* wd    = (const float*)d_in[4];
    const float* sg    = (const float*)d_in[5];
    const float* su    = (const float*)d_in[6];
    const float* sd    = (const float*)d_in[7];
    float* out = (float*)d_out;

    uintptr_t p = (uintptr_t)d_ws;
    auto alloc = [&](size_t bytes) {
        p = (p + 255) & ~(uintptr_t)255;
        void* r = (void*)p; p += bytes; return r;
    };
    int*   top_e = (int*)alloc((size_t)T_NUM * TOPK * sizeof(int));
    float* top_w = (float*)alloc((size_t)T_NUM * TOPK * sizeof(float));
    int*   offs  = (int*)alloc((E_NUM + 1) * sizeof(int));
    int*   perm  = (int*)alloc((size_t)T_NUM * TOPK * sizeof(int));
    short* xb    = (short*)alloc((size_t)T_NUM * H_DIM * 2);

    const size_t wguSz = (size_t)E_NUM * H_DIM * I_DIM * 2;    // 92.3 MB each
    const size_t shSz  = (size_t)H_DIM * SHI_DIM * 2;          // 11.5 MB each
    short* wgT = (short*)alloc(wguSz);   // [e][I][H]  bf16, k(H)-contig
    short* wuT = (short*)alloc(wguSz);   // [e][I][H]
    short* wdT = (short*)alloc(wguSz);   // [e][H][I]  k(I)-contig
    short* sgT = (short*)alloc(shSz);    // [SHI][H]
    short* suT = (short*)alloc(shSz);    // [SHI][H]
    short* sdT = (short*)alloc(shSz);    // [H][SHI]
    short* g_r   = (short*)alloc((size_t)T_NUM * TOPK * I_DIM * 2);
    short* u_r   = (short*)alloc((size_t)T_NUM * TOPK * I_DIM * 2);
    short* act_r = (short*)alloc((size_t)T_NUM * TOPK * I_DIM * 2);
    short* g_s   = (short*)alloc((size_t)T_NUM * SHI_DIM * 2);
    short* u_s   = (short*)alloc((size_t)T_NUM * SHI_DIM * 2);
    short* act_s = (short*)alloc((size_t)T_NUM * SHI_DIM * 2);
    short* dr    = (short*)alloc((size_t)T_NUM * TOPK * H_DIM * 2);  // 16.8 MB

    router_kernel<<<T_NUM, 256, 0, stream>>>(x, wgate, top_e, top_w, xb);
    perm_kernel<<<1, 256, 0, stream>>>(top_e, offs, perm);

    // weight transpose+convert: f32 [R][C] -> bf16 [C][R]
    tconv_kernel<<<dim3(I_DIM / 64, H_DIM / 64, E_NUM), 256, 0, stream>>>(wg, wgT, H_DIM, I_DIM);
    tconv_kernel<<<dim3(I_DIM / 64, H_DIM / 64, E_NUM), 256, 0, stream>>>(wu, wuT, H_DIM, I_DIM);
    tconv_kernel<<<dim3(H_DIM / 64, I_DIM / 64, E_NUM), 256, 0, stream>>>(wd, wdT, I_DIM, H_DIM);
    tconv_kernel<<<dim3(SHI_DIM / 64, H_DIM / 64, 1), 256, 0, stream>>>(sg, sgT, H_DIM, SHI_DIM);
    tconv_kernel<<<dim3(SHI_DIM / 64, H_DIM / 64, 1), 256, 0, stream>>>(su, suT, H_DIM, SHI_DIM);
    tconv_kernel<<<dim3(H_DIM / 64, SHI_DIM / 64, 1), 256, 0, stream>>>(sd, sdT, SHI_DIM, H_DIM);

    const int nmtT = T_NUM / 128;            // 8
    const int nnI = I_DIM / 128;             // 11
    const int nnH = H_DIM / 128;             // 16
    const int nnS = SHI_DIM / 128;           // 22

    // shared chain
    gemm_bf<1><<<nmtT * nnS, 256, 0, stream>>>(xb, H_DIM, H_DIM, sgT, g_s, SHI_DIM,
                                               nullptr, nullptr, nullptr, nmtT, nnS);
    gemm_bf<1><<<nmtT * nnS, 256, 0, stream>>>(xb, H_DIM, H_DIM, suT, u_s, SHI_DIM,
                                               nullptr, nullptr, nullptr, nmtT, nnS);
    swiglu_kernel<<<(T_NUM * SHI_DIM / 8 + 255) / 256, 256, 0, stream>>>(
        g_s, u_s, act_s, T_NUM * SHI_DIM / 8);
    gemm_bf<3><<<nmtT * nnH, 256, 0, stream>>>(act_s, SHI_DIM, SHI_DIM, sdT, out, H_DIM,
                                               nullptr, nullptr, nullptr, nmtT, nnH);
    // routed chain
    gemm_bf<0><<<nmtT * nnI * E_NUM, 256, 0, stream>>>(xb, H_DIM, H_DIM, wgT, g_r, I_DIM,
                                                       perm, offs, nullptr, nmtT, nnI);
    gemm_bf<0><<<nmtT * nnI * E_NUM, 256, 0, stream>>>(xb, H_DIM, H_DIM, wuT, u_r, I_DIM,
                                                       perm, offs, nullptr, nmtT, nnI);
    swiglu_kernel<<<(T_NUM * TOPK * I_DIM / 8 + 255) / 256, 256, 0, stream>>>(
        g_r, u_r, act_r, T_NUM * TOPK * I_DIM / 8);
    gemm_bf<2><<<nmtT * nnH * E_NUM, 256, 0, stream>>>(act_r, I_DIM, I_DIM, wdT, dr, H_DIM,
                                                       perm, offs, top_w, nmtT, nnH);
    // out[t] += sum_k dr[4t+k]
    combine_kernel<<<T_NUM * H_DIM / 8 / 256, 256, 0, stream>>>(dr, out);
}